// Round 1
// 1034.973 us; speedup vs baseline: 1.0134x; 1.0134x over previous
//
#include <hip/hip_runtime.h>
#include <hip/hip_bf16.h>
#include <math.h>

// Problem constants (fixed by setup_inputs)
#define B_ 64
#define T_ 32
#define H_ 1024
#define V_ 32000
#define M_ (B_ * T_)   // 2048
#define GRUB 64        // persistent GRU blocks (<=256 CUs -> co-resident)

typedef __attribute__((ext_vector_type(8))) short short8;
typedef __attribute__((ext_vector_type(4))) float f32x4;

__device__ __forceinline__ unsigned short f2bf(float f) {
  unsigned u = __float_as_uint(f);
  u = (u + 0x7FFFu + ((u >> 16) & 1u)) >> 16;   // RNE
  return (unsigned short)u;
}

__device__ __forceinline__ void async16(const void* g, void* l) {
  __builtin_amdgcn_global_load_lds(
      (const __attribute__((address_space(1))) unsigned int*)g,
      (__attribute__((address_space(3))) unsigned int*)l, 16, 0, 0);
}

// ---------------- f32 -> bf16 weight conversion (8 elts/thread) ----------------
__global__ void k_convert(const float* __restrict__ src, short* __restrict__ dst, int n8) {
  int i = blockIdx.x * blockDim.x + threadIdx.x;
  if (i >= n8) return;
  const f32x4* s = (const f32x4*)src + (size_t)i * 2;
  f32x4 a = s[0], b = s[1];
  short8 o;
  o[0] = (short)f2bf(a[0]); o[1] = (short)f2bf(a[1]);
  o[2] = (short)f2bf(a[2]); o[3] = (short)f2bf(a[3]);
  o[4] = (short)f2bf(b[0]); o[5] = (short)f2bf(b[1]);
  o[6] = (short)f2bf(b[2]); o[7] = (short)f2bf(b[3]);
  *((short8*)dst + i) = o;
}

// ---------------- embedding gather + relu + bf16; h0(bf16) init ----------------
__global__ void k_embed(const float* __restrict__ emb, const int* __restrict__ tgt,
                        const int* __restrict__ sos, const float* __restrict__ ehid,
                        short* __restrict__ xb, short* __restrict__ hb) {
  int m = blockIdx.x, tid = threadIdx.x;  // 128 threads, 8 elts each
  if (m < M_) {
    int t = m >> 6, b = m & 63;
    int token = (t == 0) ? sos[0] : tgt[b * T_ + (t - 1)];
    const f32x4* s = (const f32x4*)(emb + (size_t)token * H_) + tid * 2;
    f32x4 a = s[0], c = s[1];
    short8 o;
    #pragma unroll
    for (int j = 0; j < 4; ++j) { float v = a[j] > 0.f ? a[j] : 0.f; o[j] = (short)f2bf(v); }
    #pragma unroll
    for (int j = 0; j < 4; ++j) { float v = c[j] > 0.f ? c[j] : 0.f; o[4 + j] = (short)f2bf(v); }
    *((short8*)(xb + (size_t)m * H_) + tid) = o;
  } else {
    int b = m - M_;
    const f32x4* s = (const f32x4*)(ehid + (size_t)b * H_) + tid * 2;
    f32x4 a = s[0], c = s[1];
    short8 o;
    #pragma unroll
    for (int j = 0; j < 4; ++j) o[j] = (short)f2bf(a[j]);
    #pragma unroll
    for (int j = 0; j < 4; ++j) o[4 + j] = (short)f2bf(c[j]);
    *((short8*)(hb + (size_t)b * H_) + tid) = o;
  }
}

// ---------------- 128x128 bf16 MFMA GEMM, K=1024, BK=64 ----------------
// C[m][n] = sum_k A[m][k]*B[n][k] + bias[n].  Row tiles on blockIdx.x (fastest)
// so co-resident blocks share B column tiles -> B fetched ~once from HBM.
__global__ __launch_bounds__(256, 2)
void k_gemm(const short* __restrict__ A, const short* __restrict__ Bm,
            const float* __restrict__ bias, float* __restrict__ C,
            float* __restrict__ sumexp, int N, int do_exp) {
  __shared__ short As[128 * 64];
  __shared__ short Bs[128 * 64];
  const int tid = threadIdx.x;
  const int bm = blockIdx.x, bn = blockIdx.y;   // row tiles fastest-varying
  const int w = tid >> 6, l = tid & 63;
  const int wm = (w >> 1) * 64, wn = (w & 1) * 64;
  f32x4 acc[4][4] = {};
  const short* Ab = A + (size_t)(bm * 128) * 1024;
  const short* Bb = Bm + (size_t)(bn * 128) * 1024;

  for (int kt = 0; kt < 1024; kt += 64) {
    #pragma unroll
    for (int i = 0; i < 4; ++i) {
      int g = i * 256 + tid, r = g >> 3, cp = g & 7, c = cp ^ (r & 7);
      async16(Ab + r * 1024 + kt + c * 8, &As[g * 8]);
    }
    #pragma unroll
    for (int i = 0; i < 4; ++i) {
      int g = i * 256 + tid, r = g >> 3, cp = g & 7, c = cp ^ (r & 7);
      async16(Bb + r * 1024 + kt + c * 8, &Bs[g * 8]);
    }
    __syncthreads();
    #pragma unroll
    for (int ks = 0; ks < 2; ++ks) {
      short8 af[4], bf[4];
      #pragma unroll
      for (int mi = 0; mi < 4; ++mi) {
        int row = wm + mi * 16 + (l & 15);
        int cp = (ks * 4 + (l >> 4)) ^ (row & 7);
        af[mi] = *(const short8*)&As[row * 64 + cp * 8];
      }
      #pragma unroll
      for (int ni = 0; ni < 4; ++ni) {
        int row = wn + ni * 16 + (l & 15);
        int cp = (ks * 4 + (l >> 4)) ^ (row & 7);
        bf[ni] = *(const short8*)&Bs[row * 64 + cp * 8];
      }
      #pragma unroll
      for (int mi = 0; mi < 4; ++mi)
        #pragma unroll
        for (int ni = 0; ni < 4; ++ni)
          acc[mi][ni] = __builtin_amdgcn_mfma_f32_16x16x32_bf16(af[mi], bf[ni], acc[mi][ni], 0, 0, 0);
    }
    __syncthreads();
  }

  // C/D layout: col = lane&15, row = (lane>>4)*4 + reg
  const int row0 = bm * 128 + wm + (l >> 4) * 4;
  const int col0 = bn * 128 + wn + (l & 15);
  if (!do_exp) {
    #pragma unroll
    for (int mi = 0; mi < 4; ++mi)
      #pragma unroll
      for (int ni = 0; ni < 4; ++ni) {
        int col = col0 + ni * 16;
        float bv = bias[col];
        #pragma unroll
        for (int rg = 0; rg < 4; ++rg)
          C[(size_t)(row0 + mi * 16 + rg) * N + col] = acc[mi][ni][rg] + bv;
      }
  } else {
    #pragma unroll
    for (int mi = 0; mi < 4; ++mi) {
      float rs[4] = {0.f, 0.f, 0.f, 0.f};
      #pragma unroll
      for (int ni = 0; ni < 4; ++ni) {
        int col = col0 + ni * 16;
        float bv = bias[col];
        #pragma unroll
        for (int rg = 0; rg < 4; ++rg) {
          float v = acc[mi][ni][rg] + bv;
          C[(size_t)(row0 + mi * 16 + rg) * N + col] = v;
          rs[rg] += __expf(v);
        }
      }
      #pragma unroll
      for (int rg = 0; rg < 4; ++rg) {
        float v = rs[rg];
        #pragma unroll
        for (int off = 1; off < 16; off <<= 1) v += __shfl_xor(v, off, 64);
        if ((l & 15) == 0) atomicAdd(&sumexp[row0 + mi * 16 + rg], v);
      }
    }
  }
}

// ---------------- persistent GRU: all 32 steps in one launch ----------------
// 64 blocks x 256 threads, 1 block/CU. Block bg owns j-strip [bg*16, bg*16+16):
// W_hh slice (48x1024 bf16) resident in LDS for all steps; h_f32 for the strip
// lives in registers. Per step: h A-fragments loaded DIRECTLY from global into
// registers (32x short8/lane, all in flight -> no per-kt staging barriers),
// MFMA all 3 gates against LDS-resident W, fused gate epilogue, ping-pong
// h_bf16, grid barrier (release-RMW + relaxed poll + single acquire fence).
__global__ __launch_bounds__(256, 1)
void k_gru_persist(const short* __restrict__ Whh, const float* __restrict__ bhh,
                   const float* __restrict__ gi, const float* __restrict__ ehid,
                   short* __restrict__ hb0, short* __restrict__ hb1,
                   short* __restrict__ hs, float* __restrict__ hfin,
                   unsigned* __restrict__ barcnt) {
  __shared__ short Wlds[16 * 48 * 64];   // 96 KB: 16 K64-tiles x 48 rows x 64
  const int tid = threadIdx.x;
  const int bg = blockIdx.x;
  const int j0 = bg * 16;
  const int w = tid >> 6, l = tid & 63;

  // load resident W_hh slice: 6144 granules of 16B, XOR-swizzled
  #pragma unroll
  for (int i = 0; i < 24; ++i) {
    int idx = i * 256 + tid;
    int tile = idx / 384, rem = idx % 384;
    int r = rem >> 3, cp = rem & 7, c = cp ^ (r & 7);
    int gate = r >> 4, jr = r & 15;
    async16(Whh + ((size_t)(gate * 1024 + j0 + jr)) * 1024 + tile * 64 + c * 8,
            &Wlds[idx * 8]);
  }

  // per-thread h_f32: b = b0+rg, j = jj
  const int jj = j0 + (l & 15);
  const int b0 = w * 16 + (l >> 4) * 4;
  float hreg[4];
  #pragma unroll
  for (int rg = 0; rg < 4; ++rg) hreg[rg] = ehid[(size_t)(b0 + rg) * H_ + jj];
  const float bh_r = bhh[jj], bh_z = bhh[1024 + jj], bh_n = bhh[2048 + jj];

  // per-lane A-fragment address: row = w*16 + (l&15), col granule (l>>4)*8
  const int arow = w * 16 + (l & 15);
  const int acol = (l >> 4) * 8;

  __syncthreads();   // Wlds ready (drains vmcnt)

  for (int t = 0; t < T_; ++t) {
    const short* hin = (t & 1) ? hb1 : hb0;
    short* hout      = (t & 1) ? hb0 : hb1;

    // prefetch gi for this step (issued first, consumed last)
    float gr[4], gz[4], gn[4];
    #pragma unroll
    for (int rg = 0; rg < 4; ++rg) {
      const float* gir = gi + ((size_t)(t * 64) + b0 + rg) * 3072;
      gr[rg] = gir[jj];
      gz[rg] = gir[1024 + jj];
      gn[rg] = gir[2048 + jj];
    }

    // issue all 32 A-fragment loads (16B each, ~44 VMEM in flight)
    const short* hrow = hin + (size_t)arow * H_ + acol;
    short8 hf[32];
    #pragma unroll
    for (int ks = 0; ks < 32; ++ks)
      hf[ks] = *(const short8*)(hrow + ks * 32);

    f32x4 acc[3] = {};
    #pragma unroll
    for (int ks = 0; ks < 32; ++ks) {
      int kt64 = ks >> 1, ks2 = ks & 1;
      #pragma unroll
      for (int ga = 0; ga < 3; ++ga) {
        int brow = ga * 16 + (l & 15);
        int bcp = (ks2 * 4 + (l >> 4)) ^ (brow & 7);
        short8 bfr = *(const short8*)&Wlds[kt64 * 3072 + brow * 64 + bcp * 8];
        acc[ga] = __builtin_amdgcn_mfma_f32_16x16x32_bf16(hf[ks], bfr, acc[ga], 0, 0, 0);
      }
    }

    // fused gate epilogue
    #pragma unroll
    for (int rg = 0; rg < 4; ++rg) {
      float r = gr[rg] + acc[0][rg] + bh_r;
      r = 1.f / (1.f + __expf(-r));
      float z = gz[rg] + acc[1][rg] + bh_z;
      z = 1.f / (1.f + __expf(-z));
      float n = tanhf(gn[rg] + r * (acc[2][rg] + bh_n));
      float hn = (1.f - z) * n + z * hreg[rg];
      hreg[rg] = hn;
      short hbv = (short)f2bf(hn);
      hout[(size_t)(b0 + rg) * H_ + jj] = hbv;
      hs[((size_t)(b0 + rg) * T_ + t) * H_ + jj] = hbv;
    }
    if (t == T_ - 1) {
      #pragma unroll
      for (int rg = 0; rg < 4; ++rg) hfin[(size_t)(b0 + rg) * H_ + jj] = hreg[rg];
      break;                                  // no barrier after last step
    }

    // grid barrier: release-RMW (one L2 wb), RELAXED poll (no per-poll inv),
    // then one acquire fence (single L1/L2 inv) before next step's h loads.
    __syncthreads();                          // all waves' hout stores drained
    if (tid == 0) {
      __hip_atomic_fetch_add(barcnt, 1u, __ATOMIC_RELEASE, __HIP_MEMORY_SCOPE_AGENT);
      unsigned target = (unsigned)(GRUB * (t + 1));
      while (__hip_atomic_load(barcnt, __ATOMIC_RELAXED, __HIP_MEMORY_SCOPE_AGENT)
             < target) {}
    }
    __syncthreads();
    __builtin_amdgcn_fence(__ATOMIC_ACQUIRE, "agent");
  }
}

// ---------------- logsumexp finalize ----------------
__global__ void k_lse(float* s) {
  int i = blockIdx.x * 256 + threadIdx.x;
  if (i < M_) s[i] = logf(s[i]);
}

__global__ void k_sub(float* __restrict__ out, const float* __restrict__ lse) {
  size_t vid = (size_t)blockIdx.x * 256 + threadIdx.x;
  int r = (int)(vid / (V_ / 4));
  float ls = lse[r];
  f32x4* p = (f32x4*)out + vid;
  f32x4 v = *p;
  v[0] -= ls; v[1] -= ls; v[2] -= ls; v[3] -= ls;
  *p = v;
}

extern "C" void kernel_launch(void* const* d_in, const int* in_sizes, int n_in,
                              void* d_out, int out_size, void* d_ws, size_t ws_size,
                              hipStream_t stream) {
  const float* ehid = (const float*)d_in[1];
  const int*   tgt  = (const int*)d_in[3];
  const int*   sos  = (const int*)d_in[4];
  const float* emb  = (const float*)d_in[6];
  const float* Wih  = (const float*)d_in[7];
  const float* Whh  = (const float*)d_in[8];
  const float* bih  = (const float*)d_in[9];
  const float* bhh  = (const float*)d_in[10];
  const float* outW = (const float*)d_in[11];
  const float* outb = (const float*)d_in[12];
  float* out = (float*)d_out;

  // workspace carve-out
  char* ws = (char*)d_ws;
  size_t off = 0;
  auto alloc = [&](size_t bytes) -> void* {
    void* p = ws + off;
    off = (off + bytes + 255) & ~(size_t)255;
    return p;
  };
  short* outW_b = (short*)alloc((size_t)V_ * H_ * 2);       // 65.5 MB
  short* Wih_b  = (short*)alloc((size_t)3 * H_ * H_ * 2);   // 6.3 MB
  short* Whh_b  = (short*)alloc((size_t)3 * H_ * H_ * 2);   // 6.3 MB
  short* xb     = (short*)alloc((size_t)M_ * H_ * 2);       // 4.2 MB
  float* gi     = (float*)alloc((size_t)M_ * 3 * H_ * 4);   // 25.2 MB
  short* hs     = (short*)alloc((size_t)M_ * H_ * 2);       // 4.2 MB
  short* hb0    = (short*)alloc((size_t)B_ * H_ * 2);
  short* hb1    = (short*)alloc((size_t)B_ * H_ * 2);
  float* sume   = (float*)alloc((size_t)M_ * 4);
  unsigned* barcnt = (unsigned*)alloc(256);

  // weight conversions f32 -> bf16
  k_convert<<<V_ * H_ / 8 / 256, 256, 0, stream>>>(outW, outW_b, V_ * H_ / 8);
  k_convert<<<3 * H_ * H_ / 8 / 256, 256, 0, stream>>>(Wih, Wih_b, 3 * H_ * H_ / 8);
  k_convert<<<3 * H_ * H_ / 8 / 256, 256, 0, stream>>>(Whh, Whh_b, 3 * H_ * H_ / 8);

  // zero barrier counter + sumexp
  hipMemsetAsync(barcnt, 0, 4, stream);
  hipMemsetAsync(sume, 0, M_ * 4, stream);

  // embedding gather + relu + h0(bf16) init
  k_embed<<<M_ + B_, 128, 0, stream>>>(emb, tgt, sos, ehid, xb, hb0);

  // gi = relu(emb[tokens]) @ W_ih^T + b_ih   (M=2048, N=3072)
  dim3 g1(M_ / 128, 3 * H_ / 128);
  k_gemm<<<g1, 256, 0, stream>>>(xb, Wih_b, bih, gi, nullptr, 3 * H_, 0);

  // GRU recurrence: one persistent launch for all 32 steps
  k_gru_persist<<<GRUB, 256, 0, stream>>>(Whh_b, bhh, gi, ehid, hb0, hb1, hs,
                                          out + (size_t)B_ * T_ * V_, barcnt);

  // logits = hs @ out_W^T + out_b, fused exp-row-sum (M=2048, N=32000)
  dim3 g2(M_ / 128, V_ / 128);
  k_gemm<<<g2, 256, 0, stream>>>(hs, outW_b, outb, out, sume, V_, 1);

  // log_probs = logits - log(sum exp)
  k_lse<<<8, 256, 0, stream>>>(sume);
  k_sub<<<(int)((size_t)B_ * T_ * V_ / 4 / 256), 256, 0, stream>>>(out, sume);
}

// Round 2
// 1027.008 us; speedup vs baseline: 1.0213x; 1.0078x over previous
//
#include <hip/hip_runtime.h>
#include <hip/hip_bf16.h>
#include <math.h>

// Problem constants (fixed by setup_inputs)
#define B_ 64
#define T_ 32
#define H_ 1024
#define V_ 32000
#define M_ (B_ * T_)   // 2048
#define GRUB 64        // persistent GRU blocks (<=256 CUs -> co-resident)

typedef __attribute__((ext_vector_type(8))) short short8;
typedef __attribute__((ext_vector_type(4))) float f32x4;

__device__ __forceinline__ unsigned short f2bf(float f) {
  unsigned u = __float_as_uint(f);
  u = (u + 0x7FFFu + ((u >> 16) & 1u)) >> 16;   // RNE
  return (unsigned short)u;
}

__device__ __forceinline__ void async16(const void* g, void* l) {
  __builtin_amdgcn_global_load_lds(
      (const __attribute__((address_space(1))) unsigned int*)g,
      (__attribute__((address_space(3))) unsigned int*)l, 16, 0, 0);
}

// ---------------- f32 -> bf16 weight conversion (8 elts/thread) ----------------
__global__ void k_convert(const float* __restrict__ src, short* __restrict__ dst, int n8) {
  int i = blockIdx.x * blockDim.x + threadIdx.x;
  if (i >= n8) return;
  const f32x4* s = (const f32x4*)src + (size_t)i * 2;
  f32x4 a = s[0], b = s[1];
  short8 o;
  o[0] = (short)f2bf(a[0]); o[1] = (short)f2bf(a[1]);
  o[2] = (short)f2bf(a[2]); o[3] = (short)f2bf(a[3]);
  o[4] = (short)f2bf(b[0]); o[5] = (short)f2bf(b[1]);
  o[6] = (short)f2bf(b[2]); o[7] = (short)f2bf(b[3]);
  *((short8*)dst + i) = o;
}

// ---------------- embedding gather + relu + bf16; h0(bf16) init ----------------
__global__ void k_embed(const float* __restrict__ emb, const int* __restrict__ tgt,
                        const int* __restrict__ sos, const float* __restrict__ ehid,
                        short* __restrict__ xb, short* __restrict__ hb) {
  int m = blockIdx.x, tid = threadIdx.x;  // 128 threads, 8 elts each
  if (m < M_) {
    int t = m >> 6, b = m & 63;
    int token = (t == 0) ? sos[0] : tgt[b * T_ + (t - 1)];
    const f32x4* s = (const f32x4*)(emb + (size_t)token * H_) + tid * 2;
    f32x4 a = s[0], c = s[1];
    short8 o;
    #pragma unroll
    for (int j = 0; j < 4; ++j) { float v = a[j] > 0.f ? a[j] : 0.f; o[j] = (short)f2bf(v); }
    #pragma unroll
    for (int j = 0; j < 4; ++j) { float v = c[j] > 0.f ? c[j] : 0.f; o[4 + j] = (short)f2bf(v); }
    *((short8*)(xb + (size_t)m * H_) + tid) = o;
  } else {
    int b = m - M_;
    const f32x4* s = (const f32x4*)(ehid + (size_t)b * H_) + tid * 2;
    f32x4 a = s[0], c = s[1];
    short8 o;
    #pragma unroll
    for (int j = 0; j < 4; ++j) o[j] = (short)f2bf(a[j]);
    #pragma unroll
    for (int j = 0; j < 4; ++j) o[4 + j] = (short)f2bf(c[j]);
    *((short8*)(hb + (size_t)b * H_) + tid) = o;
  }
}

// ---------------- 128x128 bf16 MFMA GEMM, K=1024, BK=64 ----------------
// C[m][n] = sum_k A[m][k]*B[n][k] + bias[n].  Row tiles on blockIdx.x (fastest)
// so co-resident blocks share B column tiles -> B fetched ~once from HBM.
__global__ __launch_bounds__(256, 2)
void k_gemm(const short* __restrict__ A, const short* __restrict__ Bm,
            const float* __restrict__ bias, float* __restrict__ C,
            float* __restrict__ sumexp, int N, int do_exp) {
  __shared__ short As[128 * 64];
  __shared__ short Bs[128 * 64];
  const int tid = threadIdx.x;
  const int bm = blockIdx.x, bn = blockIdx.y;   // row tiles fastest-varying
  const int w = tid >> 6, l = tid & 63;
  const int wm = (w >> 1) * 64, wn = (w & 1) * 64;
  f32x4 acc[4][4] = {};
  const short* Ab = A + (size_t)(bm * 128) * 1024;
  const short* Bb = Bm + (size_t)(bn * 128) * 1024;

  for (int kt = 0; kt < 1024; kt += 64) {
    #pragma unroll
    for (int i = 0; i < 4; ++i) {
      int g = i * 256 + tid, r = g >> 3, cp = g & 7, c = cp ^ (r & 7);
      async16(Ab + r * 1024 + kt + c * 8, &As[g * 8]);
    }
    #pragma unroll
    for (int i = 0; i < 4; ++i) {
      int g = i * 256 + tid, r = g >> 3, cp = g & 7, c = cp ^ (r & 7);
      async16(Bb + r * 1024 + kt + c * 8, &Bs[g * 8]);
    }
    __syncthreads();
    #pragma unroll
    for (int ks = 0; ks < 2; ++ks) {
      short8 af[4], bf[4];
      #pragma unroll
      for (int mi = 0; mi < 4; ++mi) {
        int row = wm + mi * 16 + (l & 15);
        int cp = (ks * 4 + (l >> 4)) ^ (row & 7);
        af[mi] = *(const short8*)&As[row * 64 + cp * 8];
      }
      #pragma unroll
      for (int ni = 0; ni < 4; ++ni) {
        int row = wn + ni * 16 + (l & 15);
        int cp = (ks * 4 + (l >> 4)) ^ (row & 7);
        bf[ni] = *(const short8*)&Bs[row * 64 + cp * 8];
      }
      #pragma unroll
      for (int mi = 0; mi < 4; ++mi)
        #pragma unroll
        for (int ni = 0; ni < 4; ++ni)
          acc[mi][ni] = __builtin_amdgcn_mfma_f32_16x16x32_bf16(af[mi], bf[ni], acc[mi][ni], 0, 0, 0);
    }
    __syncthreads();
  }

  // C/D layout: col = lane&15, row = (lane>>4)*4 + reg
  const int row0 = bm * 128 + wm + (l >> 4) * 4;
  const int col0 = bn * 128 + wn + (l & 15);
  if (!do_exp) {
    #pragma unroll
    for (int mi = 0; mi < 4; ++mi)
      #pragma unroll
      for (int ni = 0; ni < 4; ++ni) {
        int col = col0 + ni * 16;
        float bv = bias[col];
        #pragma unroll
        for (int rg = 0; rg < 4; ++rg)
          C[(size_t)(row0 + mi * 16 + rg) * N + col] = acc[mi][ni][rg] + bv;
      }
  } else {
    #pragma unroll
    for (int mi = 0; mi < 4; ++mi) {
      float rs[4] = {0.f, 0.f, 0.f, 0.f};
      #pragma unroll
      for (int ni = 0; ni < 4; ++ni) {
        int col = col0 + ni * 16;
        float bv = bias[col];
        #pragma unroll
        for (int rg = 0; rg < 4; ++rg) {
          float v = acc[mi][ni][rg] + bv;
          C[(size_t)(row0 + mi * 16 + rg) * N + col] = v;
          rs[rg] += __expf(v);
        }
      }
      #pragma unroll
      for (int rg = 0; rg < 4; ++rg) {
        float v = rs[rg];
        #pragma unroll
        for (int off = 1; off < 16; off <<= 1) v += __shfl_xor(v, off, 64);
        if ((l & 15) == 0) atomicAdd(&sumexp[row0 + mi * 16 + rg], v);
      }
    }
  }
}

// ---------------- persistent GRU: all 32 steps in one launch ----------------
// 64 blocks x 256 threads, 1 block/CU. Block bg owns j-strip [bg*16, bg*16+16):
// W_hh slice (48x1024 bf16) resident in LDS for all steps; h_f32 for the strip
// lives in registers. Per step: h A-fragments loaded directly from global into
// registers, MFMA all 3 gates against LDS-resident W, fused gate epilogue,
// ping-pong h_bf16.
// Grid barrier = DISTRIBUTED FLAGS: arrival is a store-release to a per-block
// flag (own 128B line -> no same-line RMW serialization at L3); poll is wave
// 0's 64 lanes loading all 64 flags in parallel (one L3 round trip to observe
// all arrivals). gi prefetch for the next step is hoisted between arrival and
// poll so its L3 latency hides under the barrier wait.
__global__ __launch_bounds__(256, 1)
void k_gru_persist(const short* __restrict__ Whh, const float* __restrict__ bhh,
                   const float* __restrict__ gi, const float* __restrict__ ehid,
                   short* __restrict__ hb0, short* __restrict__ hb1,
                   short* __restrict__ hs, float* __restrict__ hfin,
                   unsigned* __restrict__ flags) {
  __shared__ short Wlds[16 * 48 * 64];   // 96 KB: 16 K64-tiles x 48 rows x 64
  const int tid = threadIdx.x;
  const int bg = blockIdx.x;
  const int j0 = bg * 16;
  const int w = tid >> 6, l = tid & 63;

  // load resident W_hh slice: 6144 granules of 16B, XOR-swizzled
  #pragma unroll
  for (int i = 0; i < 24; ++i) {
    int idx = i * 256 + tid;
    int tile = idx / 384, rem = idx % 384;
    int r = rem >> 3, cp = rem & 7, c = cp ^ (r & 7);
    int gate = r >> 4, jr = r & 15;
    async16(Whh + ((size_t)(gate * 1024 + j0 + jr)) * 1024 + tile * 64 + c * 8,
            &Wlds[idx * 8]);
  }

  // per-thread h_f32: b = b0+rg, j = jj
  const int jj = j0 + (l & 15);
  const int b0 = w * 16 + (l >> 4) * 4;
  float hreg[4];
  #pragma unroll
  for (int rg = 0; rg < 4; ++rg) hreg[rg] = ehid[(size_t)(b0 + rg) * H_ + jj];
  const float bh_r = bhh[jj], bh_z = bhh[1024 + jj], bh_n = bhh[2048 + jj];

  // per-lane A-fragment address: row = w*16 + (l&15), col granule (l>>4)*8
  const int arow = w * 16 + (l & 15);
  const int acol = (l >> 4) * 8;

  // gi prefetch registers (step t's values live across step t-1's barrier)
  float gr[4], gz[4], gn[4];
  #pragma unroll
  for (int rg = 0; rg < 4; ++rg) {
    const float* gir = gi + ((size_t)(b0 + rg)) * 3072;
    gr[rg] = gir[jj];
    gz[rg] = gir[1024 + jj];
    gn[rg] = gir[2048 + jj];
  }

  __syncthreads();   // Wlds ready (drains vmcnt)

  for (int t = 0; t < T_; ++t) {
    const short* hin = (t & 1) ? hb1 : hb0;
    short* hout      = (t & 1) ? hb0 : hb1;

    // issue all 32 A-fragment loads (16B each, ~32 VMEM in flight)
    const short* hrow = hin + (size_t)arow * H_ + acol;
    short8 hf[32];
    #pragma unroll
    for (int ks = 0; ks < 32; ++ks)
      hf[ks] = *(const short8*)(hrow + ks * 32);

    f32x4 acc[3] = {};
    #pragma unroll
    for (int ks = 0; ks < 32; ++ks) {
      int kt64 = ks >> 1, ks2 = ks & 1;
      #pragma unroll
      for (int ga = 0; ga < 3; ++ga) {
        int brow = ga * 16 + (l & 15);
        int bcp = (ks2 * 4 + (l >> 4)) ^ (brow & 7);
        short8 bfr = *(const short8*)&Wlds[kt64 * 3072 + brow * 64 + bcp * 8];
        acc[ga] = __builtin_amdgcn_mfma_f32_16x16x32_bf16(hf[ks], bfr, acc[ga], 0, 0, 0);
      }
    }

    // fused gate epilogue (gr/gz/gn preloaded for this step)
    #pragma unroll
    for (int rg = 0; rg < 4; ++rg) {
      float r = gr[rg] + acc[0][rg] + bh_r;
      r = 1.f / (1.f + __expf(-r));
      float z = gz[rg] + acc[1][rg] + bh_z;
      z = 1.f / (1.f + __expf(-z));
      float n = tanhf(gn[rg] + r * (acc[2][rg] + bh_n));
      float hn = (1.f - z) * n + z * hreg[rg];
      hreg[rg] = hn;
      short hbv = (short)f2bf(hn);
      hout[(size_t)(b0 + rg) * H_ + jj] = hbv;
      hs[((size_t)(b0 + rg) * T_ + t) * H_ + jj] = hbv;
    }
    if (t == T_ - 1) {
      #pragma unroll
      for (int rg = 0; rg < 4; ++rg) hfin[(size_t)(b0 + rg) * H_ + jj] = hreg[rg];
      break;                                  // no barrier after last step
    }

    // ---- distributed-flag grid barrier ----
    __syncthreads();   // every wave's hout stores issued + ack'd (vmcnt(0))
    if (tid == 0) {
      // release: waits own stores, wbL2 (flush hout to L3), then flag store
      __hip_atomic_store(&flags[(size_t)bg * 32], (unsigned)(t + 1),
                         __ATOMIC_RELEASE, __HIP_MEMORY_SCOPE_AGENT);
    }
    // prefetch gi for step t+1 while waiting (gi is read-only; regs survive inv)
    {
      #pragma unroll
      for (int rg = 0; rg < 4; ++rg) {
        const float* gir = gi + ((size_t)((t + 1) * 64) + b0 + rg) * 3072;
        gr[rg] = gir[jj];
        gz[rg] = gir[1024 + jj];
        gn[rg] = gir[2048 + jj];
      }
    }
    if (w == 0) {
      // 64 lanes observe all 64 flags in parallel; exit when all arrived
      const unsigned tgt = (unsigned)(t + 1);
      while (true) {
        unsigned v = __hip_atomic_load(&flags[(size_t)l * 32],
                                       __ATOMIC_RELAXED, __HIP_MEMORY_SCOPE_AGENT);
        if (__all(v >= tgt)) break;
      }
    }
    __syncthreads();
    __builtin_amdgcn_fence(__ATOMIC_ACQUIRE, "agent");   // one L1/L2 inv
  }
}

// ---------------- logsumexp finalize ----------------
__global__ void k_lse(float* s) {
  int i = blockIdx.x * 256 + threadIdx.x;
  if (i < M_) s[i] = logf(s[i]);
}

__global__ void k_sub(float* __restrict__ out, const float* __restrict__ lse) {
  size_t vid = (size_t)blockIdx.x * 256 + threadIdx.x;
  int r = (int)(vid / (V_ / 4));
  float ls = lse[r];
  f32x4* p = (f32x4*)out + vid;
  f32x4 v = *p;
  v[0] -= ls; v[1] -= ls; v[2] -= ls; v[3] -= ls;
  *p = v;
}

extern "C" void kernel_launch(void* const* d_in, const int* in_sizes, int n_in,
                              void* d_out, int out_size, void* d_ws, size_t ws_size,
                              hipStream_t stream) {
  const float* ehid = (const float*)d_in[1];
  const int*   tgt  = (const int*)d_in[3];
  const int*   sos  = (const int*)d_in[4];
  const float* emb  = (const float*)d_in[6];
  const float* Wih  = (const float*)d_in[7];
  const float* Whh  = (const float*)d_in[8];
  const float* bih  = (const float*)d_in[9];
  const float* bhh  = (const float*)d_in[10];
  const float* outW = (const float*)d_in[11];
  const float* outb = (const float*)d_in[12];
  float* out = (float*)d_out;

  // workspace carve-out
  char* ws = (char*)d_ws;
  size_t off = 0;
  auto alloc = [&](size_t bytes) -> void* {
    void* p = ws + off;
    off = (off + bytes + 255) & ~(size_t)255;
    return p;
  };
  short* outW_b = (short*)alloc((size_t)V_ * H_ * 2);       // 65.5 MB
  short* Wih_b  = (short*)alloc((size_t)3 * H_ * H_ * 2);   // 6.3 MB
  short* Whh_b  = (short*)alloc((size_t)3 * H_ * H_ * 2);   // 6.3 MB
  short* xb     = (short*)alloc((size_t)M_ * H_ * 2);       // 4.2 MB
  float* gi     = (float*)alloc((size_t)M_ * 3 * H_ * 4);   // 25.2 MB
  short* hs     = (short*)alloc((size_t)M_ * H_ * 2);       // 4.2 MB
  short* hb0    = (short*)alloc((size_t)B_ * H_ * 2);
  short* hb1    = (short*)alloc((size_t)B_ * H_ * 2);
  float* sume   = (float*)alloc((size_t)M_ * 4);
  unsigned* flags = (unsigned*)alloc(GRUB * 32 * 4);        // 64 flags, 128B apart

  // weight conversions f32 -> bf16
  k_convert<<<V_ * H_ / 8 / 256, 256, 0, stream>>>(outW, outW_b, V_ * H_ / 8);
  k_convert<<<3 * H_ * H_ / 8 / 256, 256, 0, stream>>>(Wih, Wih_b, 3 * H_ * H_ / 8);
  k_convert<<<3 * H_ * H_ / 8 / 256, 256, 0, stream>>>(Whh, Whh_b, 3 * H_ * H_ / 8);

  // zero barrier flags + sumexp
  hipMemsetAsync(flags, 0, GRUB * 32 * 4, stream);
  hipMemsetAsync(sume, 0, M_ * 4, stream);

  // embedding gather + relu + h0(bf16) init
  k_embed<<<M_ + B_, 128, 0, stream>>>(emb, tgt, sos, ehid, xb, hb0);

  // gi = relu(emb[tokens]) @ W_ih^T + b_ih   (M=2048, N=3072)
  dim3 g1(M_ / 128, 3 * H_ / 128);
  k_gemm<<<g1, 256, 0, stream>>>(xb, Wih_b, bih, gi, nullptr, 3 * H_, 0);

  // GRU recurrence: one persistent launch for all 32 steps
  k_gru_persist<<<GRUB, 256, 0, stream>>>(Whh_b, bhh, gi, ehid, hb0, hb1, hs,
                                          out + (size_t)B_ * T_ * V_, flags);

  // logits = hs @ out_W^T + out_b, fused exp-row-sum (M=2048, N=32000)
  dim3 g2(M_ / 128, V_ / 128);
  k_gemm<<<g2, 256, 0, stream>>>(hs, outW_b, outb, out, sume, V_, 1);

  // log_probs = logits - log(sum exp)
  k_lse<<<8, 256, 0, stream>>>(sume);
  k_sub<<<(int)((size_t)B_ * T_ * V_ / 4 / 256), 256, 0, stream>>>(out, sume);
}

// Round 3
// 949.592 us; speedup vs baseline: 1.1045x; 1.0815x over previous
//
#include <hip/hip_runtime.h>
#include <hip/hip_bf16.h>
#include <math.h>

// Problem constants (fixed by setup_inputs)
#define B_ 64
#define T_ 32
#define H_ 1024
#define V_ 32000
#define M_ (B_ * T_)   // 2048
#define GRUB 64        // persistent GRU blocks (<=256 CUs -> co-resident)

typedef __attribute__((ext_vector_type(8))) short short8;
typedef __attribute__((ext_vector_type(4))) float f32x4;

__device__ __forceinline__ unsigned short f2bf(float f) {
  unsigned u = __float_as_uint(f);
  u = (u + 0x7FFFu + ((u >> 16) & 1u)) >> 16;   // RNE
  return (unsigned short)u;
}

__device__ __forceinline__ void async16(const void* g, void* l) {
  __builtin_amdgcn_global_load_lds(
      (const __attribute__((address_space(1))) unsigned int*)g,
      (__attribute__((address_space(3))) unsigned int*)l, 16, 0, 0);
}

// ---------------- f32 -> bf16 weight conversion (8 elts/thread) ----------------
__global__ void k_convert(const float* __restrict__ src, short* __restrict__ dst, int n8) {
  int i = blockIdx.x * blockDim.x + threadIdx.x;
  if (i >= n8) return;
  const f32x4* s = (const f32x4*)src + (size_t)i * 2;
  f32x4 a = s[0], b = s[1];
  short8 o;
  o[0] = (short)f2bf(a[0]); o[1] = (short)f2bf(a[1]);
  o[2] = (short)f2bf(a[2]); o[3] = (short)f2bf(a[3]);
  o[4] = (short)f2bf(b[0]); o[5] = (short)f2bf(b[1]);
  o[6] = (short)f2bf(b[2]); o[7] = (short)f2bf(b[3]);
  *((short8*)dst + i) = o;
}

// ---------------- embedding gather + relu + bf16; h0(bf16) init ----------------
__global__ void k_embed(const float* __restrict__ emb, const int* __restrict__ tgt,
                        const int* __restrict__ sos, const float* __restrict__ ehid,
                        short* __restrict__ xb, short* __restrict__ hb) {
  int m = blockIdx.x, tid = threadIdx.x;  // 128 threads, 8 elts each
  if (m < M_) {
    int t = m >> 6, b = m & 63;
    int token = (t == 0) ? sos[0] : tgt[b * T_ + (t - 1)];
    const f32x4* s = (const f32x4*)(emb + (size_t)token * H_) + tid * 2;
    f32x4 a = s[0], c = s[1];
    short8 o;
    #pragma unroll
    for (int j = 0; j < 4; ++j) { float v = a[j] > 0.f ? a[j] : 0.f; o[j] = (short)f2bf(v); }
    #pragma unroll
    for (int j = 0; j < 4; ++j) { float v = c[j] > 0.f ? c[j] : 0.f; o[4 + j] = (short)f2bf(v); }
    *((short8*)(xb + (size_t)m * H_) + tid) = o;
  } else {
    int b = m - M_;
    const f32x4* s = (const f32x4*)(ehid + (size_t)b * H_) + tid * 2;
    f32x4 a = s[0], c = s[1];
    short8 o;
    #pragma unroll
    for (int j = 0; j < 4; ++j) o[j] = (short)f2bf(a[j]);
    #pragma unroll
    for (int j = 0; j < 4; ++j) o[4 + j] = (short)f2bf(c[j]);
    *((short8*)(hb + (size_t)b * H_) + tid) = o;
  }
}

// ---------------- 128x128 bf16 MFMA GEMM, K=1024, BK=64 ----------------
__global__ __launch_bounds__(256, 2)
void k_gemm(const short* __restrict__ A, const short* __restrict__ Bm,
            const float* __restrict__ bias, float* __restrict__ C,
            float* __restrict__ sumexp, int N, int do_exp) {
  __shared__ short As[128 * 64];
  __shared__ short Bs[128 * 64];
  const int tid = threadIdx.x;
  const int bm = blockIdx.x, bn = blockIdx.y;   // row tiles fastest-varying
  const int w = tid >> 6, l = tid & 63;
  const int wm = (w >> 1) * 64, wn = (w & 1) * 64;
  f32x4 acc[4][4] = {};
  const short* Ab = A + (size_t)(bm * 128) * 1024;
  const short* Bb = Bm + (size_t)(bn * 128) * 1024;

  for (int kt = 0; kt < 1024; kt += 64) {
    #pragma unroll
    for (int i = 0; i < 4; ++i) {
      int g = i * 256 + tid, r = g >> 3, cp = g & 7, c = cp ^ (r & 7);
      async16(Ab + r * 1024 + kt + c * 8, &As[g * 8]);
    }
    #pragma unroll
    for (int i = 0; i < 4; ++i) {
      int g = i * 256 + tid, r = g >> 3, cp = g & 7, c = cp ^ (r & 7);
      async16(Bb + r * 1024 + kt + c * 8, &Bs[g * 8]);
    }
    __syncthreads();
    #pragma unroll
    for (int ks = 0; ks < 2; ++ks) {
      short8 af[4], bf[4];
      #pragma unroll
      for (int mi = 0; mi < 4; ++mi) {
        int row = wm + mi * 16 + (l & 15);
        int cp = (ks * 4 + (l >> 4)) ^ (row & 7);
        af[mi] = *(const short8*)&As[row * 64 + cp * 8];
      }
      #pragma unroll
      for (int ni = 0; ni < 4; ++ni) {
        int row = wn + ni * 16 + (l & 15);
        int cp = (ks * 4 + (l >> 4)) ^ (row & 7);
        bf[ni] = *(const short8*)&Bs[row * 64 + cp * 8];
      }
      #pragma unroll
      for (int mi = 0; mi < 4; ++mi)
        #pragma unroll
        for (int ni = 0; ni < 4; ++ni)
          acc[mi][ni] = __builtin_amdgcn_mfma_f32_16x16x32_bf16(af[mi], bf[ni], acc[mi][ni], 0, 0, 0);
    }
    __syncthreads();
  }

  // C/D layout: col = lane&15, row = (lane>>4)*4 + reg
  const int row0 = bm * 128 + wm + (l >> 4) * 4;
  const int col0 = bn * 128 + wn + (l & 15);
  if (!do_exp) {
    #pragma unroll
    for (int mi = 0; mi < 4; ++mi)
      #pragma unroll
      for (int ni = 0; ni < 4; ++ni) {
        int col = col0 + ni * 16;
        float bv = bias[col];
        #pragma unroll
        for (int rg = 0; rg < 4; ++rg)
          C[(size_t)(row0 + mi * 16 + rg) * N + col] = acc[mi][ni][rg] + bv;
      }
  } else {
    #pragma unroll
    for (int mi = 0; mi < 4; ++mi) {
      float rs[4] = {0.f, 0.f, 0.f, 0.f};
      #pragma unroll
      for (int ni = 0; ni < 4; ++ni) {
        int col = col0 + ni * 16;
        float bv = bias[col];
        #pragma unroll
        for (int rg = 0; rg < 4; ++rg) {
          float v = acc[mi][ni][rg] + bv;
          C[(size_t)(row0 + mi * 16 + rg) * N + col] = v;
          rs[rg] += __expf(v);
        }
      }
      #pragma unroll
      for (int rg = 0; rg < 4; ++rg) {
        float v = rs[rg];
        #pragma unroll
        for (int off = 1; off < 16; off <<= 1) v += __shfl_xor(v, off, 64);
        if ((l & 15) == 0) atomicAdd(&sumexp[row0 + mi * 16 + rg], v);
      }
    }
  }
}

// ---------------- persistent GRU: all 32 steps in one launch ----------------
// 64 blocks x 256 threads, 1 block/CU. Block bg owns j-strip [bg*16, bg*16+16).
// W_hh slice is REGISTER-resident: wave w owns k in [w*256,(w+1)*256) -> 24
// short8 W-fragments/lane (96 VGPR), filled once from LDS staging at t=0.
// Per step: each wave computes partial gh over its K-quarter for ALL 64 batch
// rows (32 coherent 16B h loads in flight, 96 MFMA), cross-wave reduce via
// 49 KB LDS buffer, fused gate epilogue.
// h exchange is COHERENCE-POINT traffic (sc0 sc1 loads/stores through L3):
// no dirty-L2 h state, so the grid barrier needs NO wbl2/invl2 fences at all.
__global__ __launch_bounds__(256, 1)
void k_gru_persist(const short* __restrict__ Whh, const float* __restrict__ bhh,
                   const float* __restrict__ gi, const float* __restrict__ ehid,
                   short* __restrict__ hb0, short* __restrict__ hb1,
                   short* __restrict__ hs, float* __restrict__ hfin,
                   unsigned* __restrict__ flags) {
  __shared__ short Wlds[16 * 48 * 64];   // 96 KB staging; reused as reduce buffer
  float* red = (float*)Wlds;             // 48 tiles x 256 floats = 49 KB
  const int tid = threadIdx.x;
  const int bg = blockIdx.x;
  const int j0 = bg * 16;
  const int w = tid >> 6, l = tid & 63;

  // stage resident W_hh slice: 6144 granules of 16B, XOR-swizzled
  #pragma unroll
  for (int i = 0; i < 24; ++i) {
    int idx = i * 256 + tid;
    int tile = idx / 384, rem = idx % 384;
    int r = rem >> 3, cp = rem & 7, c = cp ^ (r & 7);
    int gate = r >> 4, jr = r & 15;
    async16(Whh + ((size_t)(gate * 1024 + j0 + jr)) * 1024 + tile * 64 + c * 8,
            &Wlds[idx * 8]);
  }

  // per-thread state: b = b0+rg, j = jj
  const int jj = j0 + (l & 15);
  const int b0 = w * 16 + (l >> 4) * 4;
  float hreg[4];
  #pragma unroll
  for (int rg = 0; rg < 4; ++rg) hreg[rg] = ehid[(size_t)(b0 + rg) * H_ + jj];
  const float bh_r = bhh[jj], bh_z = bhh[1024 + jj], bh_n = bhh[2048 + jj];

  // gi prefetch registers for step 0
  float gr[4], gz[4], gn[4];
  #pragma unroll
  for (int rg = 0; rg < 4; ++rg) {
    const float* gir = gi + ((size_t)(b0 + rg)) * 3072;
    gr[rg] = gir[jj];
    gz[rg] = gir[1024 + jj];
    gn[rg] = gir[2048 + jj];
  }

  __syncthreads();   // Wlds staged (drains LDS-DMA)

  // fill register-resident W fragments: wave w covers k in [w*256,(w+1)*256)
  short8 wreg[3][8];
  #pragma unroll
  for (int ks = 0; ks < 8; ++ks) {
    int kt64 = w * 4 + (ks >> 1), ks2 = ks & 1;
    #pragma unroll
    for (int ga = 0; ga < 3; ++ga) {
      int brow = ga * 16 + (l & 15);
      int bcp = (ks2 * 4 + (l >> 4)) ^ (brow & 7);
      wreg[ga][ks] = *(const short8*)&Wlds[kt64 * 3072 + brow * 64 + bcp * 8];
    }
  }
  __syncthreads();   // done with Wlds; LDS becomes reduce buffer

  // per-lane h-load offsets (elements): row mi*16+(l&15), k base w*256+(l>>4)*8
  size_t aoff[4];
  #pragma unroll
  for (int mi = 0; mi < 4; ++mi)
    aoff[mi] = (size_t)(mi * 16 + (l & 15)) * H_ + w * 256 + (l >> 4) * 8;

  for (int t = 0; t < T_; ++t) {
    const short* hin = (t & 1) ? hb1 : hb0;
    short* hout      = (t & 1) ? hb0 : hb1;

    // issue all 32 coherent h loads (16B, sc0 sc1: bypass L1/L2, read L3)
    short8 hf[4][8];
    #pragma unroll
    for (int mi = 0; mi < 4; ++mi)
      #pragma unroll
      for (int ks = 0; ks < 8; ++ks) {
        const short* hp = hin + aoff[mi] + ks * 32;
        asm volatile("global_load_dwordx4 %0, %1, off sc0 sc1"
                     : "=v"(hf[mi][ks]) : "v"(hp) : "memory");
      }
    asm volatile("s_waitcnt vmcnt(0)" ::: "memory");
    __builtin_amdgcn_sched_barrier(0);

    // partial gh over this wave's K-quarter, all 64 batch rows, 3 gates
    f32x4 acc[4][3] = {};
    #pragma unroll
    for (int ks = 0; ks < 8; ++ks)
      #pragma unroll
      for (int mi = 0; mi < 4; ++mi)
        #pragma unroll
        for (int ga = 0; ga < 3; ++ga)
          acc[mi][ga] = __builtin_amdgcn_mfma_f32_16x16x32_bf16(
              hf[mi][ks], wreg[ga][ks], acc[mi][ga], 0, 0, 0);

    // cross-wave reduce: write mi != w tiles to LDS, keep own mi == w in regs
    #pragma unroll
    for (int mi = 0; mi < 4; ++mi) {
      if (mi == w) continue;
      #pragma unroll
      for (int ga = 0; ga < 3; ++ga)
        *(f32x4*)&red[((size_t)(w * 12 + mi * 3 + ga)) * 256 + l * 4] = acc[mi][ga];
    }
    __syncthreads();
    f32x4 tot[3];
    #pragma unroll
    for (int ga = 0; ga < 3; ++ga) {
      tot[ga] = acc[w][ga];
      #pragma unroll
      for (int sw = 0; sw < 4; ++sw) {
        if (sw == w) continue;
        f32x4 p = *(const f32x4*)&red[((size_t)(sw * 12 + w * 3 + ga)) * 256 + l * 4];
        tot[ga][0] += p[0]; tot[ga][1] += p[1];
        tot[ga][2] += p[2]; tot[ga][3] += p[3];
      }
    }

    // fused gate epilogue; h_out via write-through coherent stores
    #pragma unroll
    for (int rg = 0; rg < 4; ++rg) {
      float r = gr[rg] + tot[0][rg] + bh_r;
      r = 1.f / (1.f + __expf(-r));
      float z = gz[rg] + tot[1][rg] + bh_z;
      z = 1.f / (1.f + __expf(-z));
      float n = tanhf(gn[rg] + r * (tot[2][rg] + bh_n));
      float hn = (1.f - z) * n + z * hreg[rg];
      hreg[rg] = hn;
      unsigned hbv = (unsigned)f2bf(hn);
      const short* hp = hout + (size_t)(b0 + rg) * H_ + jj;
      asm volatile("global_store_short %0, %1, off sc0 sc1"
                   :: "v"(hp), "v"(hbv) : "memory");
      hs[((size_t)(b0 + rg) * T_ + t) * H_ + jj] = (short)hbv;
    }
    if (t == T_ - 1) {
      #pragma unroll
      for (int rg = 0; rg < 4; ++rg) hfin[(size_t)(b0 + rg) * H_ + jj] = hreg[rg];
      break;                                  // no barrier after last step
    }

    // ---- fence-free distributed-flag grid barrier ----
    asm volatile("s_waitcnt vmcnt(0)" ::: "memory");  // own h stores at L3
    __syncthreads();                                   // all waves' stores at L3
    if (tid == 0) {
      unsigned val = (unsigned)(t + 1);
      const unsigned* fp = &flags[(size_t)bg * 32];
      asm volatile("global_store_dword %0, %1, off sc0 sc1"
                   :: "v"(fp), "v"(val) : "memory");
    }
    // prefetch gi for step t+1 while waiting (read-only; normal cached loads)
    #pragma unroll
    for (int rg = 0; rg < 4; ++rg) {
      const float* gir = gi + ((size_t)((t + 1) * 64) + b0 + rg) * 3072;
      gr[rg] = gir[jj];
      gz[rg] = gir[1024 + jj];
      gn[rg] = gir[2048 + jj];
    }
    if (w == 0) {
      // 64 lanes observe all 64 flags in parallel
      const unsigned tgt = (unsigned)(t + 1);
      while (true) {
        unsigned v = __hip_atomic_load(&flags[(size_t)l * 32],
                                       __ATOMIC_RELAXED, __HIP_MEMORY_SCOPE_AGENT);
        if (__all(v >= tgt)) break;
      }
    }
    __syncthreads();
    // no acquire fence: next step's h loads are sc0 sc1 (read coherence point)
  }
}

// ---------------- logsumexp finalize ----------------
__global__ void k_lse(float* s) {
  int i = blockIdx.x * 256 + threadIdx.x;
  if (i < M_) s[i] = logf(s[i]);
}

__global__ void k_sub(float* __restrict__ out, const float* __restrict__ lse) {
  size_t vid = (size_t)blockIdx.x * 256 + threadIdx.x;
  int r = (int)(vid / (V_ / 4));
  float ls = lse[r];
  f32x4* p = (f32x4*)out + vid;
  f32x4 v = *p;
  v[0] -= ls; v[1] -= ls; v[2] -= ls; v[3] -= ls;
  *p = v;
}

extern "C" void kernel_launch(void* const* d_in, const int* in_sizes, int n_in,
                              void* d_out, int out_size, void* d_ws, size_t ws_size,
                              hipStream_t stream) {
  const float* ehid = (const float*)d_in[1];
  const int*   tgt  = (const int*)d_in[3];
  const int*   sos  = (const int*)d_in[4];
  const float* emb  = (const float*)d_in[6];
  const float* Wih  = (const float*)d_in[7];
  const float* Whh  = (const float*)d_in[8];
  const float* bih  = (const float*)d_in[9];
  const float* bhh  = (const float*)d_in[10];
  const float* outW = (const float*)d_in[11];
  const float* outb = (const float*)d_in[12];
  float* out = (float*)d_out;

  // workspace carve-out
  char* ws = (char*)d_ws;
  size_t off = 0;
  auto alloc = [&](size_t bytes) -> void* {
    void* p = ws + off;
    off = (off + bytes + 255) & ~(size_t)255;
    return p;
  };
  short* outW_b = (short*)alloc((size_t)V_ * H_ * 2);       // 65.5 MB
  short* Wih_b  = (short*)alloc((size_t)3 * H_ * H_ * 2);   // 6.3 MB
  short* Whh_b  = (short*)alloc((size_t)3 * H_ * H_ * 2);   // 6.3 MB
  short* xb     = (short*)alloc((size_t)M_ * H_ * 2);       // 4.2 MB
  float* gi     = (float*)alloc((size_t)M_ * 3 * H_ * 4);   // 25.2 MB
  short* hs     = (short*)alloc((size_t)M_ * H_ * 2);       // 4.2 MB
  short* hb0    = (short*)alloc((size_t)B_ * H_ * 2);
  short* hb1    = (short*)alloc((size_t)B_ * H_ * 2);
  float* sume   = (float*)alloc((size_t)M_ * 4);
  unsigned* flags = (unsigned*)alloc(GRUB * 32 * 4);        // 64 flags, 128B apart

  // weight conversions f32 -> bf16
  k_convert<<<V_ * H_ / 8 / 256, 256, 0, stream>>>(outW, outW_b, V_ * H_ / 8);
  k_convert<<<3 * H_ * H_ / 8 / 256, 256, 0, stream>>>(Wih, Wih_b, 3 * H_ * H_ / 8);
  k_convert<<<3 * H_ * H_ / 8 / 256, 256, 0, stream>>>(Whh, Whh_b, 3 * H_ * H_ / 8);

  // zero barrier flags + sumexp
  hipMemsetAsync(flags, 0, GRUB * 32 * 4, stream);
  hipMemsetAsync(sume, 0, M_ * 4, stream);

  // embedding gather + relu + h0(bf16) init
  k_embed<<<M_ + B_, 128, 0, stream>>>(emb, tgt, sos, ehid, xb, hb0);

  // gi = relu(emb[tokens]) @ W_ih^T + b_ih   (M=2048, N=3072)
  dim3 g1(M_ / 128, 3 * H_ / 128);
  k_gemm<<<g1, 256, 0, stream>>>(xb, Wih_b, bih, gi, nullptr, 3 * H_, 0);

  // GRU recurrence: one persistent launch for all 32 steps
  k_gru_persist<<<GRUB, 256, 0, stream>>>(Whh_b, bhh, gi, ehid, hb0, hb1, hs,
                                          out + (size_t)B_ * T_ * V_, flags);

  // logits = hs @ out_W^T + out_b, fused exp-row-sum (M=2048, N=32000)
  dim3 g2(M_ / 128, V_ / 128);
  k_gemm<<<g2, 256, 0, stream>>>(hs, outW_b, outb, out, sume, V_, 1);

  // log_probs = logits - log(sum exp)
  k_lse<<<8, 256, 0, stream>>>(sume);
  k_sub<<<(int)((size_t)B_ * T_ * V_ / 4 / 256), 256, 0, stream>>>(out, sume);
}